// Round 1
// baseline (434.011 us; speedup 1.0000x reference)
//
#include <hip/hip_runtime.h>
#include <hip/hip_bf16.h>

// MSDeformAttn: B=4, Lq=Lv=5440, C=256, heads=8, levels=4, points=4, head_dim=32
// Shapes: (64,64),(32,32),(16,16),(8,8) -> level starts 0,4096,5120,5376
//
// Stage plan (all f32 baseline):
//   1. val  = value @ W_val  + b_val   [21760,256]
//   2. off  = query @ W_off  + b_off   [21760,256]
//   3. attn = query @ W_attn + b_attn  [21760,128]
//   4. sampling: softmax + bilinear gather -> acc [21760,256]
//   5. out  = acc @ W_out + b_out      [21760,256]

#define BM 64
#define BN 64
#define BK 16

__global__ __launch_bounds__(256) void gemm_bias_f32(
    const float* __restrict__ A, const float* __restrict__ B,
    const float* __restrict__ bias, float* __restrict__ C,
    int M, int N, int K)
{
    __shared__ __align__(16) float As[BK][BM + 4];
    __shared__ __align__(16) float Bs[BK][BN];

    const int tid = threadIdx.x;
    const int bm = blockIdx.y * BM;
    const int bn = blockIdx.x * BN;
    const int tx = tid & 15;   // 0..15 col group
    const int ty = tid >> 4;   // 0..15 row group

    // A loader: each thread loads float4 along K. row = tid>>2 (0..63), k-off = (tid&3)*4
    const int ar = tid >> 2;
    const int ak = (tid & 3) * 4;
    // B loader: k = tid>>4 (0..15), n-off = (tid&15)*4
    const int bk = tid >> 4;
    const int bn0 = (tid & 15) * 4;

    float acc[4][4] = {};

    for (int k0 = 0; k0 < K; k0 += BK) {
        float4 av = *(const float4*)(A + (size_t)(bm + ar) * K + k0 + ak);
        float4 bv = *(const float4*)(B + (size_t)(k0 + bk) * N + bn + bn0);
        __syncthreads();
        As[ak + 0][ar] = av.x;
        As[ak + 1][ar] = av.y;
        As[ak + 2][ar] = av.z;
        As[ak + 3][ar] = av.w;
        *(float4*)&Bs[bk][bn0] = bv;
        __syncthreads();
#pragma unroll
        for (int kk = 0; kk < BK; ++kk) {
            float4 a4 = *(const float4*)&As[kk][ty * 4];
            float4 b4 = *(const float4*)&Bs[kk][tx * 4];
            float a_[4] = {a4.x, a4.y, a4.z, a4.w};
            float b_[4] = {b4.x, b4.y, b4.z, b4.w};
#pragma unroll
            for (int i = 0; i < 4; ++i)
#pragma unroll
                for (int j = 0; j < 4; ++j)
                    acc[i][j] += a_[i] * b_[j];
        }
    }

#pragma unroll
    for (int i = 0; i < 4; ++i) {
        const int row = bm + ty * 4 + i;
        float4 o;
        o.x = acc[i][0] + bias[bn + tx * 4 + 0];
        o.y = acc[i][1] + bias[bn + tx * 4 + 1];
        o.z = acc[i][2] + bias[bn + tx * 4 + 2];
        o.w = acc[i][3] + bias[bn + tx * 4 + 3];
        *(float4*)(C + (size_t)row * N + bn + tx * 4) = o;
    }
}

__device__ __forceinline__ float fetch_corner(const float* __restrict__ vbase,
                                              int x, int y, int W, int H)
{
    bool valid = (x >= 0) & (x < W) & (y >= 0) & (y < H);
    int xc = min(max(x, 0), W - 1);
    int yc = min(max(y, 0), H - 1);
    float v = vbase[(size_t)(yc * W + xc) * 256];
    return valid ? v : 0.0f;
}

// One block per (b,q). 256 threads = 8 heads x 32 channels.
__global__ __launch_bounds__(256) void sample_kernel(
    const float* __restrict__ val,    // [B*Lv, 256]  (channel = h*32+d)
    const float* __restrict__ refp,   // [B, Lq, 4, 2]
    const float* __restrict__ offs,   // [B*Lq, 256]  ((h,l,p,xy))
    const float* __restrict__ attn,   // [B*Lq, 128]  ((h,l,p))
    float* __restrict__ acc_out)      // [B*Lq, 256]
{
    const int Lq = 5440;
    const int bq = blockIdx.x;          // 0..21759
    const int b = bq / Lq;
    const int h = threadIdx.x >> 5;     // head
    const int d = threadIdx.x & 31;     // channel within head

    const float* off_row = offs + (size_t)bq * 256 + h * 32;
    const float* att_row = attn + (size_t)bq * 128 + h * 16;
    const float* rp = refp + (size_t)bq * 8;

    // softmax over 16 (level,point) logits — redundant per lane, cheap
    float lg[16];
    float mx = -1e30f;
#pragma unroll
    for (int i = 0; i < 16; ++i) { lg[i] = att_row[i]; mx = fmaxf(mx, lg[i]); }
    float s = 0.0f;
#pragma unroll
    for (int i = 0; i < 16; ++i) { lg[i] = __expf(lg[i] - mx); s += lg[i]; }
    const float inv = 1.0f / s;

    const int Ws_[4] = {64, 32, 16, 8};
    const int Hs_[4] = {64, 32, 16, 8};
    const int starts_[4] = {0, 4096, 5120, 5376};

    float acc = 0.0f;
#pragma unroll
    for (int l = 0; l < 4; ++l) {
        const int W = Ws_[l], H = Hs_[l];
        const float rx = rp[l * 2 + 0], ry = rp[l * 2 + 1];
        const float* vbase = val + ((size_t)(b * 5440 + starts_[l])) * 256 + h * 32 + d;
#pragma unroll
        for (int p = 0; p < 4; ++p) {
            const int pi = l * 4 + p;
            const float w = lg[pi] * inv;
            const float ox = off_row[pi * 2 + 0];
            const float oy = off_row[pi * 2 + 1];
            // loc = ref + off/(W,H); unnormalized x = loc*W - 0.5 (align_corners=False)
            const float x = (rx + ox / (float)W) * (float)W - 0.5f;
            const float y = (ry + oy / (float)H) * (float)H - 0.5f;
            const float x0f = floorf(x), y0f = floorf(y);
            const int x0 = (int)x0f, y0 = (int)y0f;
            const float wx = x - x0f, wy = y - y0f;

            const float v00 = fetch_corner(vbase, x0,     y0,     W, H);
            const float v10 = fetch_corner(vbase, x0 + 1, y0,     W, H);
            const float v01 = fetch_corner(vbase, x0,     y0 + 1, W, H);
            const float v11 = fetch_corner(vbase, x0 + 1, y0 + 1, W, H);

            const float bil = v00 * (1.0f - wx) * (1.0f - wy)
                            + v10 * wx * (1.0f - wy)
                            + v01 * (1.0f - wx) * wy
                            + v11 * wx * wy;
            acc += w * bil;
        }
    }
    acc_out[(size_t)bq * 256 + threadIdx.x] = acc;
}

extern "C" void kernel_launch(void* const* d_in, const int* in_sizes, int n_in,
                              void* d_out, int out_size, void* d_ws, size_t ws_size,
                              hipStream_t stream) {
    const float* query  = (const float*)d_in[0];
    const float* refp   = (const float*)d_in[1];
    const float* value  = (const float*)d_in[2];
    const float* W_off  = (const float*)d_in[3];
    const float* b_off  = (const float*)d_in[4];
    const float* W_attn = (const float*)d_in[5];
    const float* b_attn = (const float*)d_in[6];
    const float* W_val  = (const float*)d_in[7];
    const float* b_val  = (const float*)d_in[8];
    const float* W_out  = (const float*)d_in[9];
    const float* b_out  = (const float*)d_in[10];
    float* out = (float*)d_out;
    float* ws = (float*)d_ws;

    const int M = 4 * 5440;  // 21760 rows

    float* v_val = ws;                          // M*256
    float* v_off = v_val + (size_t)M * 256;     // M*256
    float* v_att = v_off + (size_t)M * 256;     // M*128
    float* v_acc = v_att + (size_t)M * 128;     // M*256

    dim3 blk(256);
    gemm_bias_f32<<<dim3(256 / BN, M / BM), blk, 0, stream>>>(value, W_val, b_val, v_val, M, 256, 256);
    gemm_bias_f32<<<dim3(256 / BN, M / BM), blk, 0, stream>>>(query, W_off, b_off, v_off, M, 256, 256);
    gemm_bias_f32<<<dim3(128 / BN, M / BM), blk, 0, stream>>>(query, W_attn, b_attn, v_att, M, 128, 256);
    sample_kernel<<<dim3(M), blk, 0, stream>>>(v_val, refp, v_off, v_att, v_acc);
    gemm_bias_f32<<<dim3(256 / BN, M / BM), blk, 0, stream>>>(v_acc, W_out, b_out, out, M, 256, 256);
}

// Round 2
// 374.323 us; speedup vs baseline: 1.1595x; 1.1595x over previous
//
#include <hip/hip_runtime.h>
#include <hip/hip_bf16.h>

// MSDeformAttn: B=4, Lq=Lv=5440, C=256, heads=8, levels=4, points=4, head_dim=32
// Level shapes: (64,64),(32,32),(16,16),(8,8) -> starts 0,4096,5120,5376
//
// R1 changes vs R0 baseline (434 us):
//  - sampler: 1 wave per (b,q), lane=(head, chan-quad), float4 corner gathers.
//    R0 was 193 us @ 83% VALUBusy from per-channel redundant scalar math.
//  - gemm: 128x128 block tile, 8x8 register tile (was 64x64 / 4x4, ~47 TF).

#define BM 128
#define BN 128
#define BK 16

__global__ __launch_bounds__(256) void gemm_bias_f32(
    const float* __restrict__ A, const float* __restrict__ B,
    const float* __restrict__ bias, float* __restrict__ C,
    int M, int N, int K)
{
    __shared__ __align__(16) float As[BK][BM + 4];
    __shared__ __align__(16) float Bs[BK][BN];

    const int tid = threadIdx.x;
    const int bm = blockIdx.y * BM;
    const int bn = blockIdx.x * BN;
    const int tx = tid & 15;   // 0..15 -> 8 cols each
    const int ty = tid >> 4;   // 0..15 -> 8 rows each

    float acc[8][8] = {};

    for (int k0 = 0; k0 < K; k0 += BK) {
        float4 av[2], bv[2];
#pragma unroll
        for (int i = 0; i < 2; ++i) {
            const int idx = tid + i * 256;
            const int ar = idx >> 2, ak = (idx & 3) * 4;       // A: 128 rows x 4 quads
            av[i] = *(const float4*)(A + (size_t)(bm + ar) * K + k0 + ak);
            const int bk = idx >> 5, bn0 = (idx & 31) * 4;     // B: 16 k x 32 quads
            bv[i] = *(const float4*)(B + (size_t)(k0 + bk) * N + bn + bn0);
        }
        __syncthreads();
#pragma unroll
        for (int i = 0; i < 2; ++i) {
            const int idx = tid + i * 256;
            const int ar = idx >> 2, ak = (idx & 3) * 4;
            As[ak + 0][ar] = av[i].x;
            As[ak + 1][ar] = av[i].y;
            As[ak + 2][ar] = av[i].z;
            As[ak + 3][ar] = av[i].w;
            const int bk = idx >> 5, bn0 = (idx & 31) * 4;
            *(float4*)&Bs[bk][bn0] = bv[i];
        }
        __syncthreads();
#pragma unroll
        for (int kk = 0; kk < BK; ++kk) {
            float a_[8], b_[8];
            *(float4*)&a_[0] = *(const float4*)&As[kk][ty * 8];
            *(float4*)&a_[4] = *(const float4*)&As[kk][ty * 8 + 4];
            *(float4*)&b_[0] = *(const float4*)&Bs[kk][tx * 8];
            *(float4*)&b_[4] = *(const float4*)&Bs[kk][tx * 8 + 4];
#pragma unroll
            for (int i = 0; i < 8; ++i)
#pragma unroll
                for (int j = 0; j < 8; ++j)
                    acc[i][j] += a_[i] * b_[j];
        }
    }

#pragma unroll
    for (int i = 0; i < 8; ++i) {
        const int row = bm + ty * 8 + i;
        float* crow = C + (size_t)row * N + bn + tx * 8;
#pragma unroll
        for (int j = 0; j < 8; j += 4) {
            float4 o;
            o.x = acc[i][j + 0] + bias[bn + tx * 8 + j + 0];
            o.y = acc[i][j + 1] + bias[bn + tx * 8 + j + 1];
            o.z = acc[i][j + 2] + bias[bn + tx * 8 + j + 2];
            o.w = acc[i][j + 3] + bias[bn + tx * 8 + j + 3];
            *(float4*)(crow + j) = o;
        }
    }
}

// One WAVE per (b,q). lane: h = lane>>3 (head), d4 = (lane&7)*4 (channel quad).
// 4 waves per block -> 4 queries per block.
__global__ __launch_bounds__(256) void sample_kernel(
    const float* __restrict__ val,    // [B*Lv, 256]  (channel = h*32+d)
    const float* __restrict__ refp,   // [B, Lq, 4, 2]
    const float* __restrict__ offs,   // [B*Lq, 256]  ((h,l,p,xy))
    const float* __restrict__ attn,   // [B*Lq, 128]  ((h,l,p))
    float* __restrict__ acc_out)      // [B*Lq, 256]
{
    const int wave = threadIdx.x >> 6;
    const int lane = threadIdx.x & 63;
    const int bq = blockIdx.x * 4 + wave;    // 0..21759
    const int b = bq / 5440;
    const int h = lane >> 3;
    const int d4 = (lane & 7) * 4;

    const float* off_row = offs + (size_t)bq * 256 + h * 32;
    const float* att_row = attn + (size_t)bq * 128 + h * 16;
    const float* rp = refp + (size_t)bq * 8;

    // softmax over 16 (level,point) logits — redundant across 8 lanes of a head
    float lg[16];
    float mx = -1e30f;
#pragma unroll
    for (int i = 0; i < 16; ++i) { lg[i] = att_row[i]; mx = fmaxf(mx, lg[i]); }
    float s = 0.0f;
#pragma unroll
    for (int i = 0; i < 16; ++i) { lg[i] = __expf(lg[i] - mx); s += lg[i]; }
    const float inv = 1.0f / s;

    const int Ws_[4] = {64, 32, 16, 8};
    const int starts_[4] = {0, 4096, 5120, 5376};

    float4 acc = make_float4(0.f, 0.f, 0.f, 0.f);
#pragma unroll
    for (int l = 0; l < 4; ++l) {
        const int W = Ws_[l], H = Ws_[l];
        const float fW = (float)W, fH = (float)W;
        const float rx = rp[l * 2 + 0], ry = rp[l * 2 + 1];
        const float* vbase = val + ((size_t)(b * 5440 + starts_[l])) * 256 + h * 32 + d4;
#pragma unroll
        for (int p = 0; p < 4; ++p) {
            const int pi = l * 4 + p;
            const float aw = lg[pi] * inv;
            const float ox = off_row[pi * 2 + 0];
            const float oy = off_row[pi * 2 + 1];
            // (rx + ox/W)*W - 0.5 == rx*W + ox - 0.5 (continuity => fp reassoc safe)
            const float x = fmaf(rx, fW, ox) - 0.5f;
            const float y = fmaf(ry, fH, oy) - 0.5f;
            const float x0f = floorf(x), y0f = floorf(y);
            const int x0 = (int)x0f, y0 = (int)y0f;
            const float wx = x - x0f, wy = y - y0f;

            const bool okx0 = ((unsigned)x0 < (unsigned)W);
            const bool okx1 = ((unsigned)(x0 + 1) < (unsigned)W);
            const bool oky0 = ((unsigned)y0 < (unsigned)H);
            const bool oky1 = ((unsigned)(y0 + 1) < (unsigned)H);
            const int xc0 = min(max(x0, 0), W - 1);
            const int xc1 = min(max(x0 + 1, 0), W - 1);
            const int yc0 = min(max(y0, 0), H - 1);
            const int yc1 = min(max(y0 + 1, 0), H - 1);

            const float w00 = (okx0 & oky0) ? (1.f - wx) * (1.f - wy) * aw : 0.f;
            const float w10 = (okx1 & oky0) ? wx * (1.f - wy) * aw : 0.f;
            const float w01 = (okx0 & oky1) ? (1.f - wx) * wy * aw : 0.f;
            const float w11 = (okx1 & oky1) ? wx * wy * aw : 0.f;

            const float4 c00 = *(const float4*)(vbase + (size_t)(yc0 * W + xc0) * 256);
            const float4 c10 = *(const float4*)(vbase + (size_t)(yc0 * W + xc1) * 256);
            const float4 c01 = *(const float4*)(vbase + (size_t)(yc1 * W + xc0) * 256);
            const float4 c11 = *(const float4*)(vbase + (size_t)(yc1 * W + xc1) * 256);

            acc.x = fmaf(c00.x, w00, fmaf(c10.x, w10, fmaf(c01.x, w01, fmaf(c11.x, w11, acc.x))));
            acc.y = fmaf(c00.y, w00, fmaf(c10.y, w10, fmaf(c01.y, w01, fmaf(c11.y, w11, acc.y))));
            acc.z = fmaf(c00.z, w00, fmaf(c10.z, w10, fmaf(c01.z, w01, fmaf(c11.z, w11, acc.z))));
            acc.w = fmaf(c00.w, w00, fmaf(c10.w, w10, fmaf(c01.w, w01, fmaf(c11.w, w11, acc.w))));
        }
    }
    *(float4*)(acc_out + (size_t)bq * 256 + lane * 4) = acc;
}

extern "C" void kernel_launch(void* const* d_in, const int* in_sizes, int n_in,
                              void* d_out, int out_size, void* d_ws, size_t ws_size,
                              hipStream_t stream) {
    const float* query  = (const float*)d_in[0];
    const float* refp   = (const float*)d_in[1];
    const float* value  = (const float*)d_in[2];
    const float* W_off  = (const float*)d_in[3];
    const float* b_off  = (const float*)d_in[4];
    const float* W_attn = (const float*)d_in[5];
    const float* b_attn = (const float*)d_in[6];
    const float* W_val  = (const float*)d_in[7];
    const float* b_val  = (const float*)d_in[8];
    const float* W_out  = (const float*)d_in[9];
    const float* b_out  = (const float*)d_in[10];
    float* out = (float*)d_out;
    float* ws = (float*)d_ws;

    const int M = 4 * 5440;  // 21760 rows

    float* v_val = ws;                          // M*256
    float* v_off = v_val + (size_t)M * 256;     // M*256
    float* v_att = v_off + (size_t)M * 256;     // M*128
    float* v_acc = v_att + (size_t)M * 128;     // M*256

    dim3 blk(256);
    gemm_bias_f32<<<dim3(256 / BN, M / BM), blk, 0, stream>>>(value, W_val, b_val, v_val, M, 256, 256);
    gemm_bias_f32<<<dim3(256 / BN, M / BM), blk, 0, stream>>>(query, W_off, b_off, v_off, M, 256, 256);
    gemm_bias_f32<<<dim3(128 / BN, M / BM), blk, 0, stream>>>(query, W_attn, b_attn, v_att, M, 128, 256);
    sample_kernel<<<dim3(M / 4), blk, 0, stream>>>(v_val, refp, v_off, v_att, v_acc);
    gemm_bias_f32<<<dim3(256 / BN, M / BM), blk, 0, stream>>>(v_acc, W_out, b_out, out, M, 256, 256);
}

// Round 3
// 186.211 us; speedup vs baseline: 2.3307x; 2.0102x over previous
//
#include <hip/hip_runtime.h>

// MSDeformAttn: B=4, Lq=Lv=5440 (M=21760), C=256, heads=8, levels=4, points=4, hd=32
// Level shapes: (64,64),(32,32),(16,16),(8,8) -> starts 0,4096,5120,5376
//
// R2: f16-MFMA rewrite.
//  - R1 post-mortem: sampler 77us (L2-gather + VALU bound), 4 f32 GEMMs ~297us
//    (39 TF, no MFMA on f32 -> 157 TF ceiling; 340-block tail quantization).
//  - All GEMMs -> mfma_f32_16x16x32_f16, 128x128 tile, BK=32, f32->f16 cvt
//    fused into LDS staging. W_off|W_attn fused into one N=384 GEMM.
//  - Weights pre-transposed to Bt[n][k] f16 (B-frag: B[k=(lane>>4)*8+j][n=lane&15]).
//  - C/D layout: col=lane&15, row=(lane>>4)*4+r (m89/m91-verified).
//  - Sampler: f16 value (half fetch), 8 ch/lane, 2 queries/wave, pk_f16 accum.

typedef __attribute__((ext_vector_type(8))) _Float16 half8;
typedef __attribute__((ext_vector_type(4))) float f32x4;

__device__ __forceinline__ half8 splat8(_Float16 v) {
    half8 r = {v, v, v, v, v, v, v, v};
    return r;
}

#define M_TOTAL 21760

// ---------------- weight prep: transpose + f16 convert + concat ----------------
__global__ __launch_bounds__(256) void prep_weights(
    const float* __restrict__ W_val, const float* __restrict__ W_off,
    const float* __restrict__ W_attn, const float* __restrict__ W_out,
    const float* __restrict__ b_off, const float* __restrict__ b_attn,
    _Float16* __restrict__ wt_val, _Float16* __restrict__ wt_qcat,
    _Float16* __restrict__ wt_out, float* __restrict__ bcat)
{
    const int r = blockIdx.x;
    const int k = threadIdx.x;
    if (r < 256) {
        wt_val[r * 256 + k] = (_Float16)W_val[k * 256 + r];
    } else if (r < 640) {
        const int n = r - 256;
        const float v = (n < 256) ? W_off[k * 256 + n] : W_attn[k * 128 + (n - 256)];
        wt_qcat[n * 256 + k] = (_Float16)v;
    } else if (r < 896) {
        const int n = r - 640;
        wt_out[n * 256 + k] = (_Float16)W_out[k * 256 + n];
    } else {
        bcat[k] = b_off[k];
        if (k < 128) bcat[256 + k] = b_attn[k];
    }
}

// ---------------- f16 MFMA GEMM: C[M,NN] = A_f32[M,256] * Bt[NN,256]^T + bias ----
// 128x128 block tile, 4 waves, each wave 64x64 (4x4 grid of 16x16x32 MFMAs).
template <int NN, bool OUTF16>
__global__ __launch_bounds__(256) void gemm_mfma(
    const float* __restrict__ A, const _Float16* __restrict__ Bt,
    const float* __restrict__ bias, void* __restrict__ Cvoid)
{
    __shared__ _Float16 Ah[128 * 32];
    __shared__ _Float16 Bh[128 * 32];

    const int tid = threadIdx.x;
    const int bm = blockIdx.y * 128;
    const int bn = blockIdx.x * 128;
    const int wave = tid >> 6, lane = tid & 63;
    const int wm = (wave & 1) * 64, wn = (wave >> 1) * 64;
    const int ml = lane & 15, kq = (lane >> 4) * 8;

    const f32x4 zero4 = {0.f, 0.f, 0.f, 0.f};
    f32x4 acc[4][4];
#pragma unroll
    for (int i = 0; i < 4; ++i)
#pragma unroll
        for (int j = 0; j < 4; ++j) acc[i][j] = zero4;

    for (int kt = 0; kt < 8; ++kt) {
        const int k0 = kt * 32;
        half8 areg[2], breg[2];
#pragma unroll
        for (int u = 0; u < 2; ++u) {
            const int e = tid + u * 256;          // granule of 8 f16 along K
            const int row = e >> 2, koff = (e & 3) * 8;
            const float* src = A + (size_t)(bm + row) * 256 + k0 + koff;
            const float4 lo = *(const float4*)src;
            const float4 hi = *(const float4*)(src + 4);
            areg[u] = half8{(_Float16)lo.x, (_Float16)lo.y, (_Float16)lo.z, (_Float16)lo.w,
                            (_Float16)hi.x, (_Float16)hi.y, (_Float16)hi.z, (_Float16)hi.w};
            breg[u] = *(const half8*)(Bt + (size_t)(bn + row) * 256 + k0 + koff);
        }
        __syncthreads();
#pragma unroll
        for (int u = 0; u < 2; ++u) {
            const int e = tid + u * 256;
            *(half8*)(Ah + e * 8) = areg[u];
            *(half8*)(Bh + e * 8) = breg[u];
        }
        __syncthreads();

        half8 af[4], bf[4];
#pragma unroll
        for (int i = 0; i < 4; ++i)
            af[i] = *(const half8*)(Ah + (wm + i * 16 + ml) * 32 + kq);
#pragma unroll
        for (int j = 0; j < 4; ++j)
            bf[j] = *(const half8*)(Bh + (wn + j * 16 + ml) * 32 + kq);
#pragma unroll
        for (int i = 0; i < 4; ++i)
#pragma unroll
            for (int j = 0; j < 4; ++j)
                acc[i][j] = __builtin_amdgcn_mfma_f32_16x16x32_f16(af[i], bf[j], acc[i][j], 0, 0, 0);
    }

    const int r0 = (lane >> 4) * 4;
#pragma unroll
    for (int j = 0; j < 4; ++j) {
        const int col = bn + wn + j * 16 + ml;
        const float bj = bias[col];
#pragma unroll
        for (int i = 0; i < 4; ++i) {
            const int row = bm + wm + i * 16 + r0;
#pragma unroll
            for (int r = 0; r < 4; ++r) {
                const float v = acc[i][j][r] + bj;
                if (OUTF16)
                    ((_Float16*)Cvoid)[(size_t)(row + r) * NN + col] = (_Float16)v;
                else
                    ((float*)Cvoid)[(size_t)(row + r) * NN + col] = v;
            }
        }
    }
}

// ---------------- sampler: f16 value, 8 channels/lane, 2 queries/wave ----------
__global__ __launch_bounds__(256) void sample_f16(
    const _Float16* __restrict__ valh,   // [M,256] f16
    const float* __restrict__ refp,      // [B,Lq,4,2]
    const _Float16* __restrict__ offh,   // [M,384] f16: 0-255 offsets, 256-383 logits
    float* __restrict__ acc_out)         // [M,256] f32
{
    const int wave = threadIdx.x >> 6, lane = threadIdx.x & 63;
    const int q2 = lane >> 5, sl = lane & 31;
    const int bq = blockIdx.x * 8 + wave * 2 + q2;    // 0..21759
    const int b = bq / 5440;
    const int h = sl >> 2;          // head
    const int d8 = (sl & 3) * 8;    // channel octet within head

    const _Float16* off_row = offh + (size_t)bq * 384 + h * 32;
    const _Float16* att_row = offh + (size_t)bq * 384 + 256 + h * 16;
    const float* rp = refp + (size_t)bq * 8;

    float offv[32];
#pragma unroll
    for (int i = 0; i < 4; ++i) {
        const half8 t = *(const half8*)(off_row + i * 8);
#pragma unroll
        for (int j = 0; j < 8; ++j) offv[i * 8 + j] = (float)t[j];
    }
    float lg[16];
    {
        const half8 t0 = *(const half8*)(att_row);
        const half8 t1 = *(const half8*)(att_row + 8);
#pragma unroll
        for (int j = 0; j < 8; ++j) { lg[j] = (float)t0[j]; lg[8 + j] = (float)t1[j]; }
    }
    float mx = -1e30f;
#pragma unroll
    for (int i = 0; i < 16; ++i) mx = fmaxf(mx, lg[i]);
    float s = 0.f;
#pragma unroll
    for (int i = 0; i < 16; ++i) { lg[i] = __expf(lg[i] - mx); s += lg[i]; }
    const float inv = 1.f / s;

    const float4 rp01 = *(const float4*)rp;
    const float4 rp23 = *(const float4*)(rp + 4);
    const float rxs[4] = {rp01.x, rp01.z, rp23.x, rp23.z};
    const float rys[4] = {rp01.y, rp01.w, rp23.y, rp23.w};

    const int Ws_[4] = {64, 32, 16, 8};
    const int starts_[4] = {0, 4096, 5120, 5376};

    half8 acc = splat8((_Float16)0.f);
#pragma unroll
    for (int l = 0; l < 4; ++l) {
        const int W = Ws_[l];
        const float fW = (float)W;
        const _Float16* vbase = valh + ((size_t)(b * 5440 + starts_[l])) * 256 + h * 32 + d8;
        const float rx = rxs[l], ry = rys[l];
#pragma unroll
        for (int p = 0; p < 4; ++p) {
            const int pi = l * 4 + p;
            const float aw = lg[pi] * inv;
            // (rx + ox/W)*W - 0.5 == rx*W + ox - 0.5
            const float x = fmaf(rx, fW, offv[pi * 2 + 0]) - 0.5f;
            const float y = fmaf(ry, fW, offv[pi * 2 + 1]) - 0.5f;
            const float x0f = floorf(x), y0f = floorf(y);
            const int x0 = (int)x0f, y0 = (int)y0f;
            const float wx = x - x0f, wy = y - y0f;
            const bool okx0 = ((unsigned)x0 < (unsigned)W);
            const bool okx1 = ((unsigned)(x0 + 1) < (unsigned)W);
            const bool oky0 = ((unsigned)y0 < (unsigned)W);
            const bool oky1 = ((unsigned)(y0 + 1) < (unsigned)W);
            const int xc0 = min(max(x0, 0), W - 1);
            const int xc1 = min(max(x0 + 1, 0), W - 1);
            const int yc0 = min(max(y0, 0), W - 1);
            const int yc1 = min(max(y0 + 1, 0), W - 1);
            const float w00 = (okx0 & oky0) ? (1.f - wx) * (1.f - wy) * aw : 0.f;
            const float w10 = (okx1 & oky0) ? wx * (1.f - wy) * aw : 0.f;
            const float w01 = (okx0 & oky1) ? (1.f - wx) * wy * aw : 0.f;
            const float w11 = (okx1 & oky1) ? wx * wy * aw : 0.f;

            const half8 c00 = *(const half8*)(vbase + (size_t)(yc0 * W + xc0) * 256);
            const half8 c10 = *(const half8*)(vbase + (size_t)(yc0 * W + xc1) * 256);
            const half8 c01 = *(const half8*)(vbase + (size_t)(yc1 * W + xc0) * 256);
            const half8 c11 = *(const half8*)(vbase + (size_t)(yc1 * W + xc1) * 256);

            acc += c00 * splat8((_Float16)w00);
            acc += c10 * splat8((_Float16)w10);
            acc += c01 * splat8((_Float16)w01);
            acc += c11 * splat8((_Float16)w11);
        }
    }

    float* dst = acc_out + (size_t)bq * 256 + h * 32 + d8;
    const float4 o0 = {(float)acc[0], (float)acc[1], (float)acc[2], (float)acc[3]};
    const float4 o1 = {(float)acc[4], (float)acc[5], (float)acc[6], (float)acc[7]};
    *(float4*)dst = o0;
    *(float4*)(dst + 4) = o1;
}

extern "C" void kernel_launch(void* const* d_in, const int* in_sizes, int n_in,
                              void* d_out, int out_size, void* d_ws, size_t ws_size,
                              hipStream_t stream) {
    const float* query  = (const float*)d_in[0];
    const float* refp   = (const float*)d_in[1];
    const float* value  = (const float*)d_in[2];
    const float* W_off  = (const float*)d_in[3];
    const float* b_off  = (const float*)d_in[4];
    const float* W_attn = (const float*)d_in[5];
    const float* b_attn = (const float*)d_in[6];
    const float* W_val  = (const float*)d_in[7];
    const float* b_val  = (const float*)d_in[8];
    const float* W_out  = (const float*)d_in[9];
    const float* b_out  = (const float*)d_in[10];
    float* out = (float*)d_out;

    const size_t M = M_TOTAL;

    // workspace layout (~50.6 MB)
    _Float16* valh = (_Float16*)d_ws;                 // M*256 f16
    _Float16* offh = valh + M * 256;                  // M*384 f16
    float* acc32   = (float*)(offh + M * 384);        // M*256 f32
    _Float16* wtv  = (_Float16*)(acc32 + M * 256);    // 256*256 f16
    _Float16* wtq  = wtv + 256 * 256;                 // 384*256 f16
    _Float16* wto  = wtq + 384 * 256;                 // 256*256 f16
    float* bcat    = (float*)(wto + 256 * 256);       // 384 f32

    dim3 blk(256);
    prep_weights<<<dim3(897), blk, 0, stream>>>(W_val, W_off, W_attn, W_out,
                                                b_off, b_attn, wtv, wtq, wto, bcat);
    gemm_mfma<256, true ><<<dim3(2, 170), blk, 0, stream>>>(value, wtv, b_val, valh);
    gemm_mfma<384, true ><<<dim3(3, 170), blk, 0, stream>>>(query, wtq, bcat, offh);
    sample_f16<<<dim3(M / 8), blk, 0, stream>>>(valh, refp, offh, acc32);
    gemm_mfma<256, false><<<dim3(2, 170), blk, 0, stream>>>(acc32, wto, b_out, out);
}

// Round 4
// 185.110 us; speedup vs baseline: 2.3446x; 1.0059x over previous
//
#include <hip/hip_runtime.h>

// MSDeformAttn: B=4, Lq=Lv=5440 (M=21760), C=256, heads=8, levels=4, points=4, hd=32
// Level shapes: (64,64),(32,32),(16,16),(8,8) -> starts 0,4096,5120,5376
//
// R3: m97-style GEMMs.
//  - R2 post-mortem: sampler 50us (as predicted) but 3 GEMMs+prep ~136us —
//    staging was VGPR round-trip + f32->f16 cvt in-loop (guide §5 mistake #1).
//  - New: one f32->f16 convert pass for value/query; GEMMs stage via
//    global_load_lds width=16 (async DMA, 4 insts/kt), 2-barrier K-loop.
//  - Sampler stores f16 half8 directly (acc already f16); GEMM3 reads it.
//  - MFMA 16x16x32 f16; C/D layout col=lane&15, row=(lane>>4)*4+r (verified).

typedef __attribute__((ext_vector_type(8))) _Float16 half8;
typedef __attribute__((ext_vector_type(4))) float f32x4;

typedef __attribute__((address_space(3))) unsigned int lds_uint;
typedef const __attribute__((address_space(1))) unsigned int g_uint;

__device__ __forceinline__ void load_lds16(const _Float16* g, _Float16* l) {
    // 16B per lane; LDS dest = wave-uniform base + lane*16 (m104 semantics)
    __builtin_amdgcn_global_load_lds((g_uint*)g, (lds_uint*)l, 16, 0, 0);
}

__device__ __forceinline__ half8 splat8(_Float16 v) {
    half8 r = {v, v, v, v, v, v, v, v};
    return r;
}

#define M_TOTAL 21760

// ---------------- weight prep: transpose + f16 convert + concat ----------------
__global__ __launch_bounds__(256) void prep_weights(
    const float* __restrict__ W_val, const float* __restrict__ W_off,
    const float* __restrict__ W_attn, const float* __restrict__ W_out,
    const float* __restrict__ b_off, const float* __restrict__ b_attn,
    _Float16* __restrict__ wt_val, _Float16* __restrict__ wt_qcat,
    _Float16* __restrict__ wt_out, float* __restrict__ bcat)
{
    const int r = blockIdx.x;
    const int k = threadIdx.x;
    if (r < 256) {
        wt_val[r * 256 + k] = (_Float16)W_val[k * 256 + r];
    } else if (r < 640) {
        const int n = r - 256;
        const float v = (n < 256) ? W_off[k * 256 + n] : W_attn[k * 128 + (n - 256)];
        wt_qcat[n * 256 + k] = (_Float16)v;
    } else if (r < 896) {
        const int n = r - 640;
        wt_out[n * 256 + k] = (_Float16)W_out[k * 256 + n];
    } else {
        bcat[k] = b_off[k];
        if (k < 128) bcat[256 + k] = b_attn[k];
    }
}

// ---------------- f32 -> f16 convert (value | query), 8 elems/thread ----------
__global__ __launch_bounds__(256) void cvt_f32_f16(
    const float* __restrict__ value, const float* __restrict__ query,
    _Float16* __restrict__ val16, _Float16* __restrict__ q16)
{
    const size_t per = (size_t)M_TOTAL * 256 / 8;
    size_t idx = (size_t)blockIdx.x * 256 + threadIdx.x;
    const float* src;
    _Float16* dst;
    if (idx < per) { src = value; dst = val16; }
    else { src = query; dst = q16; idx -= per; }
    const float4 lo = *(const float4*)(src + idx * 8);
    const float4 hi = *(const float4*)(src + idx * 8 + 4);
    half8 o = {(_Float16)lo.x, (_Float16)lo.y, (_Float16)lo.z, (_Float16)lo.w,
               (_Float16)hi.x, (_Float16)hi.y, (_Float16)hi.z, (_Float16)hi.w};
    *(half8*)(dst + idx * 8) = o;
}

// ---------------- f16 MFMA GEMM: C[M,NN] = A[M,256] * Bt[NN,256]^T + bias ------
// 128x128 block tile, 4 waves (2x2 of 64x64), BK=32, global_load_lds staging.
__global__ __launch_bounds__(256) void gemm_f16(
    const _Float16* __restrict__ A, const _Float16* __restrict__ Bt,
    const float* __restrict__ bias, void* __restrict__ Cv,
    int NN, int outf16)
{
    __shared__ _Float16 Ah[128 * 32];
    __shared__ _Float16 Bh[128 * 32];

    const int tid = threadIdx.x;
    const int bm = blockIdx.y * 128;
    const int bn = blockIdx.x * 128;
    const int wave = tid >> 6, lane = tid & 63;
    const int wm = (wave & 1) * 64, wn = (wave >> 1) * 64;
    const int ml = lane & 15, kq = (lane >> 4) * 8;
    const int lr = lane >> 2;          // staging row within 16-row chunk
    const int lk = (lane & 3) * 8;     // staging k offset (f16)

    const f32x4 zero4 = {0.f, 0.f, 0.f, 0.f};
    f32x4 acc[4][4];
#pragma unroll
    for (int i = 0; i < 4; ++i)
#pragma unroll
        for (int j = 0; j < 4; ++j) acc[i][j] = zero4;

    for (int kt = 0; kt < 8; ++kt) {
        const int k0 = kt * 32;
        __syncthreads();   // all waves done reading previous tile
#pragma unroll
        for (int t = 0; t < 2; ++t) {
            const int row = wave * 32 + t * 16;   // 16-row chunk base
            load_lds16(A + (size_t)(bm + row + lr) * 256 + k0 + lk,
                       Ah + (size_t)row * 32);
            load_lds16(Bt + (size_t)(bn + row + lr) * 256 + k0 + lk,
                       Bh + (size_t)row * 32);
        }
        __syncthreads();   // compiler drains vmcnt(0) before barrier -> DMA landed

        half8 af[4], bf[4];
#pragma unroll
        for (int i = 0; i < 4; ++i)
            af[i] = *(const half8*)(Ah + (wm + i * 16 + ml) * 32 + kq);
#pragma unroll
        for (int j = 0; j < 4; ++j)
            bf[j] = *(const half8*)(Bh + (wn + j * 16 + ml) * 32 + kq);
#pragma unroll
        for (int i = 0; i < 4; ++i)
#pragma unroll
            for (int j = 0; j < 4; ++j)
                acc[i][j] = __builtin_amdgcn_mfma_f32_16x16x32_f16(af[i], bf[j], acc[i][j], 0, 0, 0);
    }

    const int r0 = (lane >> 4) * 4;
#pragma unroll
    for (int j = 0; j < 4; ++j) {
        const int col = bn + wn + j * 16 + ml;
        const float bj = bias[col];
#pragma unroll
        for (int i = 0; i < 4; ++i) {
            const size_t rbase = (size_t)(bm + wm + i * 16 + r0) * NN + col;
#pragma unroll
            for (int r = 0; r < 4; ++r) {
                const float v = acc[i][j][r] + bj;
                if (outf16)
                    ((_Float16*)Cv)[rbase + (size_t)r * NN] = (_Float16)v;
                else
                    ((float*)Cv)[rbase + (size_t)r * NN] = v;
            }
        }
    }
}

// ---------------- sampler: f16 value, 8 channels/lane, 2 queries/wave ----------
__global__ __launch_bounds__(256) void sample_f16(
    const _Float16* __restrict__ valh,   // [M,256] f16
    const float* __restrict__ refp,      // [B,Lq,4,2]
    const _Float16* __restrict__ offh,   // [M,384] f16: 0-255 offsets, 256-383 logits
    _Float16* __restrict__ acc_out)      // [M,256] f16
{
    const int wave = threadIdx.x >> 6, lane = threadIdx.x & 63;
    const int q2 = lane >> 5, sl = lane & 31;
    const int bq = blockIdx.x * 8 + wave * 2 + q2;    // 0..21759
    const int b = bq / 5440;
    const int h = sl >> 2;          // head
    const int d8 = (sl & 3) * 8;    // channel octet within head

    const _Float16* off_row = offh + (size_t)bq * 384 + h * 32;
    const _Float16* att_row = offh + (size_t)bq * 384 + 256 + h * 16;
    const float* rp = refp + (size_t)bq * 8;

    float offv[32];
#pragma unroll
    for (int i = 0; i < 4; ++i) {
        const half8 t = *(const half8*)(off_row + i * 8);
#pragma unroll
        for (int j = 0; j < 8; ++j) offv[i * 8 + j] = (float)t[j];
    }
    float lg[16];
    {
        const half8 t0 = *(const half8*)(att_row);
        const half8 t1 = *(const half8*)(att_row + 8);
#pragma unroll
        for (int j = 0; j < 8; ++j) { lg[j] = (float)t0[j]; lg[8 + j] = (float)t1[j]; }
    }
    float mx = -1e30f;
#pragma unroll
    for (int i = 0; i < 16; ++i) mx = fmaxf(mx, lg[i]);
    float s = 0.f;
#pragma unroll
    for (int i = 0; i < 16; ++i) { lg[i] = __expf(lg[i] - mx); s += lg[i]; }
    const float inv = 1.f / s;

    const float4 rp01 = *(const float4*)rp;
    const float4 rp23 = *(const float4*)(rp + 4);
    const float rxs[4] = {rp01.x, rp01.z, rp23.x, rp23.z};
    const float rys[4] = {rp01.y, rp01.w, rp23.y, rp23.w};

    const int Ws_[4] = {64, 32, 16, 8};
    const int starts_[4] = {0, 4096, 5120, 5376};

    half8 acc = splat8((_Float16)0.f);
#pragma unroll
    for (int l = 0; l < 4; ++l) {
        const int W = Ws_[l];
        const float fW = (float)W;
        const _Float16* vbase = valh + ((size_t)(b * 5440 + starts_[l])) * 256 + h * 32 + d8;
        const float rx = rxs[l], ry = rys[l];
#pragma unroll
        for (int p = 0; p < 4; ++p) {
            const int pi = l * 4 + p;
            const float aw = lg[pi] * inv;
            // (rx + ox/W)*W - 0.5 == rx*W + ox - 0.5
            const float x = fmaf(rx, fW, offv[pi * 2 + 0]) - 0.5f;
            const float y = fmaf(ry, fW, offv[pi * 2 + 1]) - 0.5f;
            const float x0f = floorf(x), y0f = floorf(y);
            const int x0 = (int)x0f, y0 = (int)y0f;
            const float wx = x - x0f, wy = y - y0f;
            const bool okx0 = ((unsigned)x0 < (unsigned)W);
            const bool okx1 = ((unsigned)(x0 + 1) < (unsigned)W);
            const bool oky0 = ((unsigned)y0 < (unsigned)W);
            const bool oky1 = ((unsigned)(y0 + 1) < (unsigned)W);
            const int xc0 = min(max(x0, 0), W - 1);
            const int xc1 = min(max(x0 + 1, 0), W - 1);
            const int yc0 = min(max(y0, 0), W - 1);
            const int yc1 = min(max(y0 + 1, 0), W - 1);
            const float w00 = (okx0 & oky0) ? (1.f - wx) * (1.f - wy) * aw : 0.f;
            const float w10 = (okx1 & oky0) ? wx * (1.f - wy) * aw : 0.f;
            const float w01 = (okx0 & oky1) ? (1.f - wx) * wy * aw : 0.f;
            const float w11 = (okx1 & oky1) ? wx * wy * aw : 0.f;

            const half8 c00 = *(const half8*)(vbase + (size_t)(yc0 * W + xc0) * 256);
            const half8 c10 = *(const half8*)(vbase + (size_t)(yc0 * W + xc1) * 256);
            const half8 c01 = *(const half8*)(vbase + (size_t)(yc1 * W + xc0) * 256);
            const half8 c11 = *(const half8*)(vbase + (size_t)(yc1 * W + xc1) * 256);

            acc += c00 * splat8((_Float16)w00);
            acc += c10 * splat8((_Float16)w10);
            acc += c01 * splat8((_Float16)w01);
            acc += c11 * splat8((_Float16)w11);
        }
    }

    *(half8*)(acc_out + (size_t)bq * 256 + h * 32 + d8) = acc;
}

extern "C" void kernel_launch(void* const* d_in, const int* in_sizes, int n_in,
                              void* d_out, int out_size, void* d_ws, size_t ws_size,
                              hipStream_t stream) {
    const float* query  = (const float*)d_in[0];
    const float* refp   = (const float*)d_in[1];
    const float* value  = (const float*)d_in[2];
    const float* W_off  = (const float*)d_in[3];
    const float* b_off  = (const float*)d_in[4];
    const float* W_attn = (const float*)d_in[5];
    const float* b_attn = (const float*)d_in[6];
    const float* W_val  = (const float*)d_in[7];
    const float* b_val  = (const float*)d_in[8];
    const float* W_out  = (const float*)d_in[9];
    const float* b_out  = (const float*)d_in[10];
    float* out = (float*)d_out;

    const size_t M = M_TOTAL;

    // workspace (~50.6 MB); acc16 aliases val16 (val16 fully consumed by GEMM1
    // before the sampler writes acc16 — same-stream ordering).
    _Float16* val16 = (_Float16*)d_ws;                // M*256
    _Float16* q16   = val16 + M * 256;                // M*256
    _Float16* valh  = q16 + M * 256;                  // M*256
    _Float16* offh  = valh + M * 256;                 // M*384
    _Float16* wtv   = offh + M * 384;                 // 256*256
    _Float16* wtq   = wtv + 256 * 256;                // 384*256
    _Float16* wto   = wtq + 384 * 256;                // 256*256
    float* bcat     = (float*)(wto + 256 * 256);      // 384
    _Float16* acc16 = val16;                          // alias

    dim3 blk(256);
    prep_weights<<<dim3(897), blk, 0, stream>>>(W_val, W_off, W_attn, W_out,
                                                b_off, b_attn, wtv, wtq, wto, bcat);
    cvt_f32_f16<<<dim3(2 * M * 256 / 8 / 256), blk, 0, stream>>>(value, query, val16, q16);
    gemm_f16<<<dim3(2, 170), blk, 0, stream>>>(val16, wtv, b_val, valh, 256, 1);
    gemm_f16<<<dim3(3, 170), blk, 0, stream>>>(q16, wtq, bcat, offh, 384, 1);
    sample_f16<<<dim3(M / 8), blk, 0, stream>>>(valh, refp, offh, acc16);
    gemm_f16<<<dim3(2, 170), blk, 0, stream>>>(acc16, wto, b_out, out, 256, 0);
}